// Round 14
// baseline (86.252 us; speedup 1.0000x reference)
//
#include <hip/hip_runtime.h>

// LearnableDemosaick: B=16,H=512,W=512,K=8,f=5, fp32.
// out = is_green ? mosaick : softmax_k(sel_conv) . green_conv
// is_green = (y%2)==(x%2). Edge-clamped 5x5 cross-correlation.
//
// Round-14: chip-wide phase alignment theory. Grid==residency => stage /
// compute / drain phases never overlap anywhere on the chip (T_main ~16us
// vs ~6us HBM + ~3us issue). Fix: 2 tiles per block (image b and b+8 at the
// same (x,y)), cross-tile pipeline: stage A -> barrier -> prefetch B to regs
// -> compute A -> pack B to LDS buf 2 -> barrier -> compute B. Tile B's HBM
// latency hides under tile A's compute. Per-tile structure = verified
// R10/R13 path (TH=16, LDS greens).

typedef float f32x16 __attribute__((ext_vector_type(16)));
typedef short s16x8  __attribute__((ext_vector_type(8)));

#define HH 512
#define WW 512
#define TW 64
#define TH 16
#define RS 80     // LDS row stride (bf16 elems) = 160 B
#define NROW 20   // TH + 4
#define NEL 72    // staged elems per row

__device__ __forceinline__ unsigned short bf16rne(float x) {
    unsigned u = __float_as_uint(x);
    u += 0x7fffu + ((u >> 16) & 1u);
    return (unsigned short)(u >> 16);
}
__device__ __forceinline__ int pk2(float hi, float lo) {
    return (int)((((unsigned)bf16rne(hi)) << 16) | (unsigned)bf16rne(lo));
}
__device__ __forceinline__ float hi16(int v) { return __uint_as_float(((unsigned)v) & 0xffff0000u); }
__device__ __forceinline__ float lo16(int v) { return __uint_as_float(((unsigned)v) << 16); }
__device__ __forceinline__ float bf2f(unsigned short s) {
    return __uint_as_float(((unsigned)s) << 16);
}

// ---- setup: build the 6 per-lane A fragments once into ws ----
__global__ void build_frags_kernel(const float* __restrict__ sf,
                                   const float* __restrict__ gf,
                                   short* __restrict__ ws)
{
    const int lane = threadIdx.x;     // 0..63
    const int mm   = lane & 31;
    const int h    = (lane >> 5) & 1;
    const int c    = mm >> 1;
    const bool tg  = mm & 1;
    const bool chok = mm < 16;
    const float* fb = tg ? gf : sf;

    s16x8 A[6];
#pragma unroll
    for (int f = 0; f < 6; ++f)
#pragma unroll
        for (int j = 0; j < 8; ++j) A[f][j] = 0;

#pragma unroll
    for (int j = 0; j < 8; ++j) {
        const int dx0 = j - 1;
        if (dx0 >= 0 && dx0 < 5 && chok) {
            A[0][j] = (short)bf16rne(fb[((h)     * 5 + dx0) * 8 + c]);
            A[1][j] = (short)bf16rne(fb[((2 + h) * 5 + dx0) * 8 + c]);
            if (h == 0)
                A[2][j] = (short)bf16rne(fb[(4 * 5 + dx0) * 8 + c]);
        }
        const int dx1 = j;
        if (dx1 < 5 && chok) {
            if (h == 1)
                A[3][j] = (short)bf16rne(fb[(0 * 5 + dx1) * 8 + c]);
            A[4][j] = (short)bf16rne(fb[((1 + h) * 5 + dx1) * 8 + c]);
            A[5][j] = (short)bf16rne(fb[((3 + h) * 5 + dx1) * 8 + c]);
        }
    }
    s16x8* dst = (s16x8*)(ws + lane * 48);
#pragma unroll
    for (int f = 0; f < 6; ++f) dst[f] = A[f];
}

__device__ __forceinline__ void stage_border(
    unsigned short* dst, const float* img, int tileX, int tileY, int tid)
{
    for (int i = tid; i < NROW * NEL; i += 256) {
        int r = i / NEL, e = i - NEL * r;
        int gy = min(max(tileY - 2 + r, 0), HH - 1);
        int gx = min(max(tileX - 2 + e, 0), WW - 1);
        dst[r * RS + e] = bf16rne(img[(size_t)gy * WW + gx]);
    }
}

__device__ __forceinline__ void compute_image(
    const unsigned short* __restrict__ tileS,
    const s16x8& Aa0, const s16x8& Ab0, const s16x8& Ac0,
    const s16x8& Aa1, const s16x8& Ab1, const s16x8& Ac1,
    float* __restrict__ outp, int tileX, int tileY, int w, int n, int h)
{
    const int* tb = (const int*)tileS;     // 40 ints per row
#pragma unroll
    for (int pp = 0; pp < 2; ++pp) {
        const int Rl = 4 * w + 2 * pp;     // local pair base row (even)
        const int y  = tileY + Rl;
        const int ia = (Rl + h) * 40 + n;

        union { int4 v; s16x8 s; } Ba, Bb, Bc;
        Ba.v.x = tb[ia];       Ba.v.y = tb[ia + 1];
        Ba.v.z = tb[ia + 2];   Ba.v.w = tb[ia + 3];
        Bb.v.x = tb[ia + 80];  Bb.v.y = tb[ia + 81];
        Bb.v.z = tb[ia + 82];  Bb.v.w = tb[ia + 83];
        Bc.v.x = tb[ia + 160]; Bc.v.y = tb[ia + 161];
        Bc.v.z = tb[ia + 162]; Bc.v.w = tb[ia + 163];

        f32x16 a0 = (f32x16)(0.f), a1 = (f32x16)(0.f);
        a0 = __builtin_amdgcn_mfma_f32_32x32x16_bf16(Aa0, Ba.s, a0, 0, 0, 0);
        a1 = __builtin_amdgcn_mfma_f32_32x32x16_bf16(Aa1, Ba.s, a1, 0, 0, 0);
        a0 = __builtin_amdgcn_mfma_f32_32x32x16_bf16(Ab0, Bb.s, a0, 0, 0, 0);
        a1 = __builtin_amdgcn_mfma_f32_32x32x16_bf16(Ab1, Bb.s, a1, 0, 0, 0);
        a0 = __builtin_amdgcn_mfma_f32_32x32x16_bf16(Ac0, Bc.s, a0, 0, 0, 0);
        a1 = __builtin_amdgcn_mfma_f32_32x32x16_bf16(Ac1, Bc.s, a1, 0, 0, 0);

        float den0 = 0.f, num0 = 0.f, den1 = 0.f, num1 = 0.f;
#pragma unroll
        for (int j = 0; j < 4; ++j) {
            float e0 = __expf(a0[2 * j]);
            den0 += e0;
            num0 = fmaf(e0, a0[2 * j + 1], num0);
            float e1 = __expf(a1[2 * j]);
            den1 += e1;
            num1 = fmaf(e1, a1[2 * j + 1], num1);
        }
        int ndA  = pk2(num0, den0);
        int ndB  = pk2(num1, den1);
        int ndA2 = __shfl_xor(ndA, 32);
        int ndB2 = __shfl_xor(ndB, 32);
        const float numA = num0 + hi16(ndA2);
        const float denA = den0 + lo16(ndA2);
        const float numB = num1 + hi16(ndB2);
        const float denB = den1 + lo16(ndB2);
        const float interpA = numA * __builtin_amdgcn_rcpf(denA);
        const float interpB = numB * __builtin_amdgcn_rcpf(denB);

        if (h == 0) {
            const int x0 = tileX + 2 * n;                  // even
            const float greenA = bf2f(tileS[(Rl + 2) * RS + 2 * n + 2]);
            const float greenB = bf2f(tileS[(Rl + 3) * RS + 2 * n + 3]);
            float2 stA; stA.x = greenA;  stA.y = interpA;
            float2 stB; stB.x = interpB; stB.y = greenB;
            *(float2*)(outp + (size_t)y * WW + x0)       = stA;
            *(float2*)(outp + (size_t)(y + 1) * WW + x0) = stB;
        }
    }
}

__global__ __launch_bounds__(256) void demosaick_kernel(
    const float* __restrict__ mos,   // [B,1,H,W]
    const short* __restrict__ frg,   // per-lane A fragments (from ws)
    float* __restrict__ out)         // [B,1,H,W]
{
    __shared__ alignas(16) unsigned short tile0[NROW * RS];
    __shared__ alignas(16) unsigned short tile1[NROW * RS];

    const int tid   = threadIdx.x;
    const int bx    = blockIdx.x;
    const int by    = blockIdx.y;
    const int bimg  = blockIdx.z;          // 0..7 -> images bimg, bimg+8
    const int tileX = bx * TW;             // even
    const int tileY = by * TH;             // even
    const float* img0 = mos + (size_t)bimg * HH * WW;
    const float* img1 = img0 + (size_t)8 * HH * WW;
    float* outp0 = out + (size_t)bimg * HH * WW;
    float* outp1 = outp0 + (size_t)8 * HH * WW;

    // ---- per-lane A fragments (coalesced dwordx4) ----
    const int lane = tid & 63;
    const int w    = tid >> 6;
    const int n    = lane & 31;
    const int h    = lane >> 5;

    const s16x8* wsf = (const s16x8*)(frg + lane * 48);
    const s16x8 Aa0 = wsf[0], Ab0 = wsf[1], Ac0 = wsf[2];
    const s16x8 Aa1 = wsf[3], Ab1 = wsf[4], Ac1 = wsf[5];

    const bool interior = (bx >= 1) && (bx <= 6) && (by >= 1) && (by <= 30);
    const int r = tid / 9, s = tid - 9 * r;          // chunk coords (tid<180)

    // ---- stage tile A (image bimg) ----
    if (interior) {
        if (tid < 180) {
            const float2* src = (const float2*)(img0 + (size_t)(tileY - 2 + r) * WW
                                                + (tileX - 2 + 8 * s));
            float2 v0 = src[0], v1 = src[1], v2 = src[2], v3 = src[3];
            int4 d;
            d.x = pk2(v0.y, v0.x);
            d.y = pk2(v1.y, v1.x);
            d.z = pk2(v2.y, v2.x);
            d.w = pk2(v3.y, v3.x);
            *(int4*)&tile0[r * RS + 8 * s] = d;
        }
    } else {
        stage_border(tile0, img0, tileX, tileY, tid);
    }
    __syncthreads();

    // ---- prefetch tile B (image bimg+8) into regs; in flight during A ----
    float2 q0, q1, q2, q3;
    if (interior && tid < 180) {
        const float2* src = (const float2*)(img1 + (size_t)(tileY - 2 + r) * WW
                                            + (tileX - 2 + 8 * s));
        q0 = src[0]; q1 = src[1]; q2 = src[2]; q3 = src[3];
    }

    // ---- compute image A ----
    compute_image(tile0, Aa0, Ab0, Ac0, Aa1, Ab1, Ac1,
                  outp0, tileX, tileY, w, n, h);

    // ---- pack tile B into the second LDS buffer ----
    if (interior) {
        if (tid < 180) {
            int4 d;
            d.x = pk2(q0.y, q0.x);
            d.y = pk2(q1.y, q1.x);
            d.z = pk2(q2.y, q2.x);
            d.w = pk2(q3.y, q3.x);
            *(int4*)&tile1[r * RS + 8 * s] = d;
        }
    } else {
        stage_border(tile1, img1, tileX, tileY, tid);
    }
    __syncthreads();

    // ---- compute image B ----
    compute_image(tile1, Aa0, Ab0, Ac0, Aa1, Ab1, Ac1,
                  outp1, tileX, tileY, w, n, h);
}

extern "C" void kernel_launch(void* const* d_in, const int* in_sizes, int n_in,
                              void* d_out, int out_size, void* d_ws, size_t ws_size,
                              hipStream_t stream) {
    const float* mos = (const float*)d_in[0];
    const float* sf  = (const float*)d_in[1];
    const float* gf  = (const float*)d_in[2];
    float* out = (float*)d_out;
    short* ws  = (short*)d_ws;

    const int B = in_sizes[0] / (HH * WW);     // 16

    build_frags_kernel<<<1, 64, 0, stream>>>(sf, gf, ws);

    dim3 grid(WW / TW, HH / TH, B / 2);        // (8, 32, 8) = 2048 blocks
    dim3 block(256);
    demosaick_kernel<<<grid, block, 0, stream>>>(mos, (const short*)ws, out);
}

// Round 15
// 85.696 us; speedup vs baseline: 1.0065x; 1.0065x over previous
//
#include <hip/hip_runtime.h>

// LearnableDemosaick: B=16,H=512,W=512,K=8,f=5, fp32.
// out = is_green ? mosaick : softmax_k(sel_conv) . green_conv
// is_green = (y%2)==(x%2). Edge-clamped 5x5 cross-correlation.
//
// FINAL (= R10, best measured 85.2us): MFMA implicit conv.
//  * 32x32x16 bf16 MFMA: D[ch][px], A = filters with Bayer parity absorbed
//    into k-slots, B = bf16 LDS pixel tile (4B-aligned ds_read_b32).
//  * channel slots m=2c+t (t=sel/grn): softmax pairing in-lane, one packed
//    xor32 shuffle per row; no-max softmax (logits bounded), v_rcp epilogue.
//  * per-lane A fragments built ONCE by a 1-block setup kernel into d_ws;
//    main kernel loads them with 6 coalesced dwordx4 (R10's -4.8us).
// Measured decomposition: bench ~= 69us harness floor (268MB ws poison fill
// + out poison + restore) + 16.4us kernel (R11 3x-launch measurement), of
// which ~5.3us is the HBM floor. Six structural attacks on the remaining
// ~11us (R7,R9,R12,R13,R14) all neutral within +-1.5us noise.

typedef float f32x16 __attribute__((ext_vector_type(16)));
typedef short s16x8  __attribute__((ext_vector_type(8)));

#define HH 512
#define WW 512
#define TW 64
#define TH 16
#define RS 80     // LDS row stride (bf16 elems) = 160 B
#define NROW 20   // TH + 4
#define NEL 72    // staged elems per row (9 chunks of 8)

__device__ __forceinline__ unsigned short bf16rne(float x) {
    unsigned u = __float_as_uint(x);
    u += 0x7fffu + ((u >> 16) & 1u);
    return (unsigned short)(u >> 16);
}
__device__ __forceinline__ int pk2(float hi, float lo) {
    return (int)((((unsigned)bf16rne(hi)) << 16) | (unsigned)bf16rne(lo));
}
__device__ __forceinline__ float hi16(int v) { return __uint_as_float(((unsigned)v) & 0xffff0000u); }
__device__ __forceinline__ float lo16(int v) { return __uint_as_float(((unsigned)v) << 16); }

// ---- setup: build the 6 per-lane A fragments once into ws ----
__global__ void build_frags_kernel(const float* __restrict__ sf,
                                   const float* __restrict__ gf,
                                   short* __restrict__ ws)
{
    const int lane = threadIdx.x;     // 0..63
    const int mm   = lane & 31;
    const int h    = (lane >> 5) & 1;
    const int c    = mm >> 1;
    const bool tg  = mm & 1;
    const bool chok = mm < 16;
    const float* fb = tg ? gf : sf;

    s16x8 A[6];
#pragma unroll
    for (int f = 0; f < 6; ++f)
#pragma unroll
        for (int j = 0; j < 8; ++j) A[f][j] = 0;

#pragma unroll
    for (int j = 0; j < 8; ++j) {
        const int dx0 = j - 1;
        if (dx0 >= 0 && dx0 < 5 && chok) {
            A[0][j] = (short)bf16rne(fb[((h)     * 5 + dx0) * 8 + c]);
            A[1][j] = (short)bf16rne(fb[((2 + h) * 5 + dx0) * 8 + c]);
            if (h == 0)
                A[2][j] = (short)bf16rne(fb[(4 * 5 + dx0) * 8 + c]);
        }
        const int dx1 = j;
        if (dx1 < 5 && chok) {
            if (h == 1)
                A[3][j] = (short)bf16rne(fb[(0 * 5 + dx1) * 8 + c]);
            A[4][j] = (short)bf16rne(fb[((1 + h) * 5 + dx1) * 8 + c]);
            A[5][j] = (short)bf16rne(fb[((3 + h) * 5 + dx1) * 8 + c]);
        }
    }
    s16x8* dst = (s16x8*)(ws + lane * 48);
#pragma unroll
    for (int f = 0; f < 6; ++f) dst[f] = A[f];
}

__global__ __launch_bounds__(256) void demosaick_kernel(
    const float* __restrict__ mos,   // [B,1,H,W]
    const short* __restrict__ frg,   // per-lane A fragments (from ws)
    float* __restrict__ out)         // [B,1,H,W]
{
    __shared__ alignas(16) unsigned short tileS[NROW * RS];

    const int tid   = threadIdx.x;
    const int bx    = blockIdx.x;
    const int by    = blockIdx.y;
    const int bimg  = blockIdx.z;
    const int tileX = bx * TW;    // even
    const int tileY = by * TH;    // even
    const float* img = mos + (size_t)bimg * HH * WW;

    const bool interior = (bx >= 1) && (bx <= 6) && (by >= 1) && (by <= 30);
    if (interior) {
        if (tid < 180) {                       // 20 rows x 9 chunks of 8 elems
            int r = tid / 9, s = tid - 9 * r;
            const float2* src = (const float2*)(img + (size_t)(tileY - 2 + r) * WW
                                                + (tileX - 2 + 8 * s));
            float2 v0 = src[0], v1 = src[1], v2 = src[2], v3 = src[3];
            int4 d;
            d.x = pk2(v0.y, v0.x);
            d.y = pk2(v1.y, v1.x);
            d.z = pk2(v2.y, v2.x);
            d.w = pk2(v3.y, v3.x);
            *(int4*)&tileS[r * RS + 8 * s] = d;
        }
    } else {
        for (int i = tid; i < NROW * NEL; i += 256) {
            int r = i / NEL, e = i - NEL * r;
            int gy = min(max(tileY - 2 + r, 0), HH - 1);
            int gx = min(max(tileX - 2 + e, 0), WW - 1);
            tileS[r * RS + e] = bf16rne(img[(size_t)gy * WW + gx]);
        }
    }

    const int lane = tid & 63;
    const int w    = tid >> 6;
    const int n    = lane & 31;
    const int h    = lane >> 5;

    const s16x8* wsf = (const s16x8*)(frg + lane * 48);
    const s16x8 Aa0 = wsf[0], Ab0 = wsf[1], Ac0 = wsf[2];
    const s16x8 Aa1 = wsf[3], Ab1 = wsf[4], Ac1 = wsf[5];

    __syncthreads();

    const int* tb = (const int*)tileS;     // 40 ints per row
    float* outp = out + (size_t)bimg * HH * WW;

#pragma unroll
    for (int pp = 0; pp < 2; ++pp) {
        const int Rl = 4 * w + 2 * pp;
        const int y  = tileY + Rl;
        const int ia = (Rl + h) * 40 + n;

        union { int4 v; s16x8 s; } Ba, Bb, Bc;
        Ba.v.x = tb[ia];       Ba.v.y = tb[ia + 1];
        Ba.v.z = tb[ia + 2];   Ba.v.w = tb[ia + 3];
        Bb.v.x = tb[ia + 80];  Bb.v.y = tb[ia + 81];
        Bb.v.z = tb[ia + 82];  Bb.v.w = tb[ia + 83];
        Bc.v.x = tb[ia + 160]; Bc.v.y = tb[ia + 161];
        Bc.v.z = tb[ia + 162]; Bc.v.w = tb[ia + 163];

        f32x16 acc = (f32x16)(0.f);
        acc = __builtin_amdgcn_mfma_f32_32x32x16_bf16(Aa0, Ba.s, acc, 0, 0, 0);
        acc = __builtin_amdgcn_mfma_f32_32x32x16_bf16(Ab0, Bb.s, acc, 0, 0, 0);
        acc = __builtin_amdgcn_mfma_f32_32x32x16_bf16(Ac0, Bc.s, acc, 0, 0, 0);
        {
            float den = 0.f, num = 0.f;
#pragma unroll
            for (int j = 0; j < 4; ++j) {
                float e = __expf(acc[2 * j]);
                den += e;
                num = fmaf(e, acc[2 * j + 1], num);
            }
            int nd  = pk2(num, den);
            int nd2 = __shfl_xor(nd, 32);
            num += hi16(nd2);
            den += lo16(nd2);
            const float interp = num * __builtin_amdgcn_rcpf(den);
            if (h == 0) {
                const int x0 = tileX + 2 * n;
                const float green = img[(size_t)y * WW + x0];
                float2 st; st.x = green; st.y = interp;
                *(float2*)(outp + (size_t)y * WW + x0) = st;
            }
        }

        f32x16 acc2 = (f32x16)(0.f);
        acc2 = __builtin_amdgcn_mfma_f32_32x32x16_bf16(Aa1, Ba.s, acc2, 0, 0, 0);
        acc2 = __builtin_amdgcn_mfma_f32_32x32x16_bf16(Ab1, Bb.s, acc2, 0, 0, 0);
        acc2 = __builtin_amdgcn_mfma_f32_32x32x16_bf16(Ac1, Bc.s, acc2, 0, 0, 0);
        {
            float den = 0.f, num = 0.f;
#pragma unroll
            for (int j = 0; j < 4; ++j) {
                float e = __expf(acc2[2 * j]);
                den += e;
                num = fmaf(e, acc2[2 * j + 1], num);
            }
            int nd  = pk2(num, den);
            int nd2 = __shfl_xor(nd, 32);
            num += hi16(nd2);
            den += lo16(nd2);
            const float interp = num * __builtin_amdgcn_rcpf(den);
            if (h == 0) {
                const int x0 = tileX + 2 * n;
                const float green = img[(size_t)(y + 1) * WW + x0 + 1];
                float2 st; st.x = interp; st.y = green;
                *(float2*)(outp + (size_t)(y + 1) * WW + x0) = st;
            }
        }
    }
}

extern "C" void kernel_launch(void* const* d_in, const int* in_sizes, int n_in,
                              void* d_out, int out_size, void* d_ws, size_t ws_size,
                              hipStream_t stream) {
    const float* mos = (const float*)d_in[0];
    const float* sf  = (const float*)d_in[1];
    const float* gf  = (const float*)d_in[2];
    float* out = (float*)d_out;
    short* ws  = (short*)d_ws;

    const int B = in_sizes[0] / (HH * WW);     // 16

    build_frags_kernel<<<1, 64, 0, stream>>>(sf, gf, ws);

    dim3 grid(WW / TW, HH / TH, B);            // (8, 32, 16) = 4096 blocks
    dim3 block(256);
    demosaick_kernel<<<grid, block, 0, stream>>>(mos, (const short*)ws, out);
}